// Round 13
// baseline (257.531 us; speedup 1.0000x reference)
//
#include <hip/hip_runtime.h>

#define TLEN 512
#define XSTR 516      // x LDS row stride (floats)
#define HSTR 40       // h LDS row stride (bf16 elems): 80B rows, 16B-aligned frags

typedef __attribute__((ext_vector_type(8))) short bf16x8;
typedef __attribute__((ext_vector_type(4))) float f32x4;

#define LOG2E_ 1.44269504f
#define S2F_   2.88539008f   // 2*log2e; c kept in S2F*c space

__device__ __forceinline__ float fexp2_(float x) {
#if __has_builtin(__builtin_amdgcn_exp2f)
    return __builtin_amdgcn_exp2f(x);      // raw v_exp_f32
#else
    return __expf(x * 0.69314718056f);
#endif
}
__device__ __forceinline__ float frcp_(float x) {
#if __has_builtin(__builtin_amdgcn_rcpf)
    return __builtin_amdgcn_rcpf(x);       // raw v_rcp_f32 (~1 ulp)
#else
    return 1.0f / x;
#endif
}
__device__ __forceinline__ unsigned short f2bf(float f) {   // RNE (setup only)
    unsigned u = __float_as_uint(f);
    u += 0x7FFFu + ((u >> 16) & 1u);
    return (unsigned short)(u >> 16);
}
__device__ __forceinline__ float bf2f(unsigned short b) {
    return __uint_as_float(((unsigned)b) << 16);
}

// Gate pre-activations arrive PRE-SCALED (folded into weights/biases):
//  sigmoid rows (i,f,o): a = -log2e * x  -> sig = rcp(1+exp2(a))
//  tanh row    (g):      a = 2log2e * x  -> S2F*tanh = S2F - 2*S2F*rcp(1+exp2(a))
// c kept in S2F*c space -> tanh(c) = 1 - 2*rcp(1+exp2(c')).
__device__ __forceinline__ float lstm_nl(const f32x4 a, float& cS) {
    const float i_ = frcp_(1.0f + fexp2_(a[0]));
    const float f_ = frcp_(1.0f + fexp2_(a[1]));
    const float rg = frcp_(1.0f + fexp2_(a[2]));
    const float g_ = S2F_ - 2.0f * S2F_ * rg;      // S2F*tanh(g)
    const float o_ = frcp_(1.0f + fexp2_(a[3]));
    cS = f_ * cS + i_ * g_;
    const float rc = frcp_(1.0f + fexp2_(cS));
    return o_ * (1.0f - 2.0f * rc);
}

// Block = 16 batch cols, 8 waves (512 thr). BALANCED: wave w owns tile w of
// BOTH layers (L0: 3 MFMAs, L1: 6 MFMAs = 9 each), so no straggler at the
// per-step barrier. MIXED-GATE tiles: tile-row = 4*jj + gate; weight row =
// gate*32 + 4*tile + jj. Lane (col=lane&15, kq=lane>>4): D rows kq*4+r =
// all 4 gates of j = 4*tile+kq -> NL fully lane-local.
// fp32 accuracy: bf16 hi/lo split, 3 MFMAs per matvec.
// L1 lags L0 by one step; both parts read only prev-parity buffers ->
// independent within a step, one barrier per step, shared h0[prv] frags.
// NOTE (R8-R12 post-mortems): 16 waves/1 barrier domain, 2 blocks/CU with
// ballast cols, late-pack fusion, 5-chain MFMA splits, and rev5 write
// permutation ALL regress vs this structure. The 27M SQ_LDS_BANK_CONFLICT
// is free 2-way read aliasing (m136), not a fixable stall.
__global__ __launch_bounds__(512, 1)
void lstm2_mfma(const float* __restrict__ x,
                const float* __restrict__ w_ih0,
                const float* __restrict__ w_hh0,
                const float* __restrict__ b_ih0,
                const float* __restrict__ b_hh0,
                const float* __restrict__ w_ih1,
                const float* __restrict__ w_hh1,
                const float* __restrict__ b_ih1,
                const float* __restrict__ b_hh1,
                const float* __restrict__ fc1_w,
                const float* __restrict__ fc1_b,
                const float* __restrict__ fc2_w,
                const float* __restrict__ fc2_b,
                float* __restrict__ out)
{
    __shared__ float x_lds[16][XSTR];
    __shared__ unsigned short h0b[2][2][16][HSTR];  // [dbuf][hi/lo][col][k]
    __shared__ unsigned short h1b[2][2][16][HSTR];
    __shared__ float h1f[16][36];                   // final h1 (f32) for head

    const int tid  = threadIdx.x;
    const int wid  = tid >> 6;    // = tile index (0..7)
    const int lane = tid & 63;
    const int col  = lane & 15;   // batch col
    const int kq   = lane >> 4;
    const int b0   = blockIdx.x * 16;

    // ---- stage x (coalesced float4) ----
    for (int i4 = tid; i4 < (16 * TLEN) / 4; i4 += 512) {
        const int idx = i4 * 4;
        const int row = idx >> 9, cx = idx & 511;
        float4 v = *(const float4*)(x + (long)(b0 + row) * TLEN + cx);
        *(float4*)&x_lds[row][cx] = v;
    }
    for (int i = tid; i < 2 * 2 * 16 * HSTR; i += 512) {
        ((unsigned short*)h0b)[i] = 0;
        ((unsigned short*)h1b)[i] = 0;
    }

    const int tile = wid;
    const int jj   = 4 * tile + kq;    // this lane's j (both layers)
    const int k0   = kq * 8;

    // A-frag weight row (mixed-gate tile ordering); per-row exp2 pre-scale
    const int   arow = (col & 3) * 32 + 4 * tile + (col >> 2);
    const float sA   = ((col & 3) == 2) ? S2F_ : -LOG2E_;

    bf16x8 wL0hi, wL0lo, wIhi, wIlo, wHhi, wHlo;
    #pragma unroll
    for (int e = 0; e < 8; ++e) {
        float w;
        unsigned short hb;
        w = sA * w_hh0[arow * 32 + k0 + e]; hb = f2bf(w);
        wL0hi[e] = (short)hb; wL0lo[e] = (short)f2bf(w - bf2f(hb));
        w = sA * w_ih1[arow * 32 + k0 + e]; hb = f2bf(w);
        wIhi[e]  = (short)hb; wIlo[e]  = (short)f2bf(w - bf2f(hb));
        w = sA * w_hh1[arow * 32 + k0 + e]; hb = f2bf(w);
        wHhi[e]  = (short)hb; wHlo[e]  = (short)f2bf(w - bf2f(hb));
    }

    // bias / x-weight for this lane's D rows: row(r) = r*32 + 4*tile + kq
    f32x4 biasL0, biasL1, xwv;
    #pragma unroll
    for (int r = 0; r < 4; ++r) {
        const int  row = r * 32 + 4 * tile + kq;
        const float sr = (r == 2) ? S2F_ : -LOG2E_;
        biasL0[r] = sr * (b_ih0[row] + b_hh0[row]);
        biasL1[r] = sr * (b_ih1[row] + b_hh1[row]);
        xwv[r]    = sr * w_ih0[row];
    }

    float cL0 = 0.0f, cL1 = 0.0f;     // cell states (S2F-scaled)
    __syncthreads();

#define PACK_H(BUF, PAR, HV, J)                                                  \
    do {                                                                         \
        const unsigned u_ = __float_as_uint(HV);                                 \
        BUF[PAR][0][col][J] = (unsigned short)(u_ >> 16);                        \
        const float lof_ = (HV) - __uint_as_float(u_ & 0xFFFF0000u);             \
        BUF[PAR][1][col][J] = (unsigned short)(__float_as_uint(lof_) >> 16);     \
    } while (0)

// One timestep; CUR/PRV compile-time -> LDS addrs fold to base+immediate.
#define STEP_BODY(T, CUR, PRV)                                                   \
    do {                                                                         \
        const int t_ = (T);                                                      \
        const bf16x8 bhi = *(const bf16x8*)&h0b[PRV][0][col][k0];                \
        const bf16x8 blo = *(const bf16x8*)&h0b[PRV][1][col][k0];                \
        if (t_ < TLEN) {                                                         \
            const float xt = x_lds[col][t_];                                     \
            f32x4 aL0 = biasL0 + xwv * xt;                                       \
            aL0 = __builtin_amdgcn_mfma_f32_16x16x32_bf16(wL0hi, bhi, aL0, 0, 0, 0); \
            aL0 = __builtin_amdgcn_mfma_f32_16x16x32_bf16(wL0hi, blo, aL0, 0, 0, 0); \
            aL0 = __builtin_amdgcn_mfma_f32_16x16x32_bf16(wL0lo, bhi, aL0, 0, 0, 0); \
            const float hv = lstm_nl(aL0, cL0);                                  \
            PACK_H(h0b, CUR, hv, jj);                                            \
        }                                                                        \
        if (t_ >= 1) {                                                           \
            const bf16x8 chi = *(const bf16x8*)&h1b[CUR][0][col][k0];            \
            const bf16x8 clo = *(const bf16x8*)&h1b[CUR][1][col][k0];            \
            f32x4 aI = biasL1;                                                   \
            f32x4 aH = {0.0f, 0.0f, 0.0f, 0.0f};                                 \
            aI = __builtin_amdgcn_mfma_f32_16x16x32_bf16(wIhi, bhi, aI, 0, 0, 0); \
            aH = __builtin_amdgcn_mfma_f32_16x16x32_bf16(wHhi, chi, aH, 0, 0, 0); \
            aI = __builtin_amdgcn_mfma_f32_16x16x32_bf16(wIhi, blo, aI, 0, 0, 0); \
            aH = __builtin_amdgcn_mfma_f32_16x16x32_bf16(wHhi, clo, aH, 0, 0, 0); \
            aI = __builtin_amdgcn_mfma_f32_16x16x32_bf16(wIlo, bhi, aI, 0, 0, 0); \
            aH = __builtin_amdgcn_mfma_f32_16x16x32_bf16(wHlo, chi, aH, 0, 0, 0); \
            const f32x4 a = aI + aH;                                             \
            const float hv = lstm_nl(a, cL1);                                    \
            PACK_H(h1b, PRV, hv, jj);                                            \
            if (t_ == TLEN) h1f[col][jj] = hv;                                   \
        }                                                                        \
        __syncthreads();                                                         \
    } while (0)

    STEP_BODY(0, 0, 1);
    for (int tt = 1; tt < TLEN; tt += 2) {
        STEP_BODY(tt,     1, 0);
        STEP_BODY(tt + 1, 0, 1);
    }
#undef STEP_BODY
#undef PACK_H

    // ---- head: out[b] = fc2( relu( fc1 . h1_T ) ) + fc2_b, by wave 0 ----
    if (wid == 0) {
        float s = 0.0f;
        #pragma unroll
        for (int it = 0; it < 4; ++it) {
            const int r = kq * 4 + it;    // fc1 row in [0,16)
            float acc = fc1_b[r];
            #pragma unroll
            for (int qq = 0; qq < 8; ++qq) {
                const float4 wv = *(const float4*)(fc1_w + r * 32 + qq * 4);
                const float4 hv = *(const float4*)&h1f[col][qq * 4];
                acc += wv.x * hv.x + wv.y * hv.y + wv.z * hv.z + wv.w * hv.w;
            }
            s += fmaxf(acc, 0.0f) * fc2_w[r];
        }
        s += __shfl_xor(s, 16);
        s += __shfl_xor(s, 32);
        if (lane < 16) out[b0 + col] = s + fc2_b[0];
    }
}

extern "C" void kernel_launch(void* const* d_in, const int* in_sizes, int n_in,
                              void* d_out, int out_size, void* d_ws, size_t ws_size,
                              hipStream_t stream) {
    const float* x     = (const float*)d_in[0];
    const float* w_ih0 = (const float*)d_in[1];
    const float* w_hh0 = (const float*)d_in[2];
    const float* b_ih0 = (const float*)d_in[3];
    const float* b_hh0 = (const float*)d_in[4];
    const float* w_ih1 = (const float*)d_in[5];
    const float* w_hh1 = (const float*)d_in[6];
    const float* b_ih1 = (const float*)d_in[7];
    const float* b_hh1 = (const float*)d_in[8];
    const float* fc1_w = (const float*)d_in[9];
    const float* fc1_b = (const float*)d_in[10];
    const float* fc2_w = (const float*)d_in[11];
    const float* fc2_b = (const float*)d_in[12];
    float* out = (float*)d_out;

    dim3 grid(4096 / 16);   // 256 blocks, 1 per CU
    dim3 block(512);        // 8 balanced waves -> 2 per SIMD
    hipLaunchKernelGGL(lstm2_mfma, grid, block, 0, stream,
                       x, w_ih0, w_hh0, b_ih0, b_hh0,
                       w_ih1, w_hh1, b_ih1, b_hh1,
                       fc1_w, fc1_b, fc2_w, fc2_b, out);
}

// Round 14
// 235.132 us; speedup vs baseline: 1.0953x; 1.0953x over previous
//
#include <hip/hip_runtime.h>

#define TLEN 512
#define XSTR 516      // x LDS row stride (floats)
#define HSTR 40       // h LDS row stride (bf16 elems): 80B rows, 16B-aligned frags

typedef __attribute__((ext_vector_type(8))) short bf16x8;
typedef __attribute__((ext_vector_type(4))) float f32x4;

#define LOG2E_ 1.44269504f
#define S2F_   2.88539008f   // 2*log2e; c kept in S2F*c space

__device__ __forceinline__ float fexp2_(float x) {
#if __has_builtin(__builtin_amdgcn_exp2f)
    return __builtin_amdgcn_exp2f(x);      // raw v_exp_f32
#else
    return __expf(x * 0.69314718056f);
#endif
}
__device__ __forceinline__ float frcp_(float x) {
#if __has_builtin(__builtin_amdgcn_rcpf)
    return __builtin_amdgcn_rcpf(x);       // raw v_rcp_f32 (~1 ulp)
#else
    return 1.0f / x;
#endif
}
__device__ __forceinline__ unsigned short f2bf(float f) {   // RNE (setup only)
    unsigned u = __float_as_uint(f);
    u += 0x7FFFu + ((u >> 16) & 1u);
    return (unsigned short)(u >> 16);
}
__device__ __forceinline__ float bf2f(unsigned short b) {
    return __uint_as_float(((unsigned)b) << 16);
}

// Gate pre-activations arrive PRE-SCALED (folded into weights/biases):
//  sigmoid rows (i,f,o): a = -log2e * x  -> sig = rcp(1+exp2(a))
//  tanh row    (g):      a = 2log2e * x  -> S2F*tanh = S2F - 2*S2F*rcp(1+exp2(a))
// c kept in S2F*c space -> tanh(c) = 1 - 2*rcp(1+exp2(c')).
__device__ __forceinline__ float lstm_nl(const f32x4 a, float& cS) {
    const float i_ = frcp_(1.0f + fexp2_(a[0]));
    const float f_ = frcp_(1.0f + fexp2_(a[1]));
    const float rg = frcp_(1.0f + fexp2_(a[2]));
    const float g_ = S2F_ - 2.0f * S2F_ * rg;      // S2F*tanh(g)
    const float o_ = frcp_(1.0f + fexp2_(a[3]));
    cS = f_ * cS + i_ * g_;
    const float rc = frcp_(1.0f + fexp2_(cS));
    return o_ * (1.0f - 2.0f * rc);
}

// FINAL STRUCTURE (R7 base + R12's same-era-positive micro-items, no rev5).
// Block = 16 batch cols, 8 balanced waves; wave w owns tile w of BOTH layers
// (L0: 3 MFMAs, L1: 6 MFMAs as two parallel 3-chains). MIXED-GATE tiles:
// weight row = gate*32 + 4*tile + jj. Lane (col=lane&15, kq=lane>>4):
// D rows kq*4+r = all 4 gates of j=4*tile+kq -> NL fully lane-local.
// fp32 accuracy: bf16 hi/lo split, Whi*hhi + Whi*hlo + Wlo*hhi per matvec.
// L1 lags L0 one step; all reads hit prev-parity buffers -> 1 barrier/step.
// Steady loop branch-free (t=0 / t=TLEN peeled); 3 MFMA chains issued
// round-robin before any NL; x prefetched one step ahead in a register.
//
// STRUCTURAL FLOOR (R8-R13 evidence): per-step all-to-all (each gate row
// needs all 32 h's, produced by all 8 waves) forces block-wide sync each of
// the 513 steps; LDS-flag desync degenerates to a barrier. Wave-parallelism
// escapes measured and rejected: 16 waves/1 domain (R8, +12%), 2 blocks/CU
// via ballast (R9, +63%). Per-SIMD-step: VALU busy ~600cy (trans floor
// ~160cy), MFMA ~280cy, ~360cy irreducible barrier/chain stall. Cross-era
// bench noise is ~8-9% (R13 == R7 source, 257 vs 235).
__global__ __launch_bounds__(512, 1)
void lstm2_mfma(const float* __restrict__ x,
                const float* __restrict__ w_ih0,
                const float* __restrict__ w_hh0,
                const float* __restrict__ b_ih0,
                const float* __restrict__ b_hh0,
                const float* __restrict__ w_ih1,
                const float* __restrict__ w_hh1,
                const float* __restrict__ b_ih1,
                const float* __restrict__ b_hh1,
                const float* __restrict__ fc1_w,
                const float* __restrict__ fc1_b,
                const float* __restrict__ fc2_w,
                const float* __restrict__ fc2_b,
                float* __restrict__ out)
{
    __shared__ float x_lds[16][XSTR];
    __shared__ unsigned short h0b[2][2][16][HSTR];  // [dbuf][hi/lo][col][k]
    __shared__ unsigned short h1b[2][2][16][HSTR];
    __shared__ float h1f[16][36];                   // final h1 (f32) for head

    const int tid  = threadIdx.x;
    const int wid  = tid >> 6;    // = tile index (0..7)
    const int lane = tid & 63;
    const int col  = lane & 15;   // batch col
    const int kq   = lane >> 4;
    const int b0   = blockIdx.x * 16;

    // ---- stage x (coalesced float4) ----
    for (int i4 = tid; i4 < (16 * TLEN) / 4; i4 += 512) {
        const int idx = i4 * 4;
        const int row = idx >> 9, cx = idx & 511;
        float4 v = *(const float4*)(x + (long)(b0 + row) * TLEN + cx);
        *(float4*)&x_lds[row][cx] = v;
    }
    for (int i = tid; i < 2 * 2 * 16 * HSTR; i += 512) {
        ((unsigned short*)h0b)[i] = 0;
        ((unsigned short*)h1b)[i] = 0;
    }

    const int tile = wid;
    const int jj   = 4 * tile + kq;    // this lane's j (both layers)
    const int k0   = kq * 8;

    // A-frag weight row (mixed-gate tile ordering); per-row exp2 pre-scale
    const int   arow = (col & 3) * 32 + 4 * tile + (col >> 2);
    const float sA   = ((col & 3) == 2) ? S2F_ : -LOG2E_;

    bf16x8 wL0hi, wL0lo, wIhi, wIlo, wHhi, wHlo;
    #pragma unroll
    for (int e = 0; e < 8; ++e) {
        float w;
        unsigned short hb;
        w = sA * w_hh0[arow * 32 + k0 + e]; hb = f2bf(w);
        wL0hi[e] = (short)hb; wL0lo[e] = (short)f2bf(w - bf2f(hb));
        w = sA * w_ih1[arow * 32 + k0 + e]; hb = f2bf(w);
        wIhi[e]  = (short)hb; wIlo[e]  = (short)f2bf(w - bf2f(hb));
        w = sA * w_hh1[arow * 32 + k0 + e]; hb = f2bf(w);
        wHhi[e]  = (short)hb; wHlo[e]  = (short)f2bf(w - bf2f(hb));
    }

    // bias / x-weight for this lane's D rows: row(r) = r*32 + 4*tile + kq
    f32x4 biasL0, biasL1, xwv;
    #pragma unroll
    for (int r = 0; r < 4; ++r) {
        const int  row = r * 32 + 4 * tile + kq;
        const float sr = (r == 2) ? S2F_ : -LOG2E_;
        biasL0[r] = sr * (b_ih0[row] + b_hh0[row]);
        biasL1[r] = sr * (b_ih1[row] + b_hh1[row]);
        xwv[r]    = sr * w_ih0[row];
    }
    const f32x4 zero4 = {0.0f, 0.0f, 0.0f, 0.0f};

    float cL0 = 0.0f, cL1 = 0.0f;     // cell states (S2F-scaled)
    __syncthreads();

#define PACK_H(BUF, PAR, HV, J)                                                  \
    do {                                                                         \
        const unsigned u_ = __float_as_uint(HV);                                 \
        BUF[PAR][0][col][J] = (unsigned short)(u_ >> 16);                        \
        const float lof_ = (HV) - __uint_as_float(u_ & 0xFFFF0000u);             \
        BUF[PAR][1][col][J] = (unsigned short)(__float_as_uint(lof_) >> 16);     \
    } while (0)

    // ---- peel t = 0: L0 only (h0 buffers zero; skip MFMAs entirely) ----
    float xcur;
    {
        const float xt = x_lds[col][0];
        f32x4 aL0 = biasL0 + xwv * xt;
        const float hv = lstm_nl(aL0, cL0);
        PACK_H(h0b, 0, hv, jj);
        xcur = x_lds[col][1];
        __syncthreads();
    }

// Branch-free steady step (t = 1..511): shared ds_reads, three MFMA chains
// (aL0/aI/aH) issued round-robin BEFORE any NL, early h0 pack, then L1.
// CUR/PRV compile-time literals -> LDS addrs fold to base+immediate.
#define STEP_BODY(T, CUR, PRV)                                                   \
    do {                                                                         \
        const int t_ = (T);                                                      \
        const bf16x8 bhi = *(const bf16x8*)&h0b[PRV][0][col][k0];                \
        const bf16x8 blo = *(const bf16x8*)&h0b[PRV][1][col][k0];                \
        const bf16x8 chi = *(const bf16x8*)&h1b[CUR][0][col][k0];                \
        const bf16x8 clo = *(const bf16x8*)&h1b[CUR][1][col][k0];                \
        f32x4 aL0 = biasL0 + xwv * xcur;                                         \
        f32x4 aI, aH;                                                            \
        aL0 = __builtin_amdgcn_mfma_f32_16x16x32_bf16(wL0hi, bhi, aL0,   0, 0, 0); \
        aI  = __builtin_amdgcn_mfma_f32_16x16x32_bf16(wIhi,  bhi, biasL1, 0, 0, 0); \
        aH  = __builtin_amdgcn_mfma_f32_16x16x32_bf16(wHhi,  chi, zero4, 0, 0, 0); \
        aL0 = __builtin_amdgcn_mfma_f32_16x16x32_bf16(wL0hi, blo, aL0, 0, 0, 0); \
        aI  = __builtin_amdgcn_mfma_f32_16x16x32_bf16(wIhi,  blo, aI,  0, 0, 0); \
        aH  = __builtin_amdgcn_mfma_f32_16x16x32_bf16(wHhi,  clo, aH,  0, 0, 0); \
        aL0 = __builtin_amdgcn_mfma_f32_16x16x32_bf16(wL0lo, bhi, aL0, 0, 0, 0); \
        aI  = __builtin_amdgcn_mfma_f32_16x16x32_bf16(wIlo,  bhi, aI,  0, 0, 0); \
        aH  = __builtin_amdgcn_mfma_f32_16x16x32_bf16(wHlo,  chi, aH,  0, 0, 0); \
        const float xnext = x_lds[col][t_ + 1];                                  \
        const float hv0 = lstm_nl(aL0, cL0);                                     \
        PACK_H(h0b, CUR, hv0, jj);                                               \
        const f32x4 aL1 = aI + aH;                                               \
        const float hv1 = lstm_nl(aL1, cL1);                                     \
        PACK_H(h1b, PRV, hv1, jj);                                               \
        xcur = xnext;                                                            \
        __syncthreads();                                                         \
    } while (0)

    STEP_BODY(1, 1, 0);
    for (int tt = 2; tt < TLEN; tt += 2) {
        STEP_BODY(tt,     0, 1);
        STEP_BODY(tt + 1, 1, 0);
    }
#undef STEP_BODY

    // ---- peel t = TLEN (CUR=0, PRV=1): L1 only -> h1[511] into h1f ----
    {
        const bf16x8 bhi = *(const bf16x8*)&h0b[1][0][col][k0];
        const bf16x8 blo = *(const bf16x8*)&h0b[1][1][col][k0];
        const bf16x8 chi = *(const bf16x8*)&h1b[0][0][col][k0];
        const bf16x8 clo = *(const bf16x8*)&h1b[0][1][col][k0];
        f32x4 aI, aH;
        aI = __builtin_amdgcn_mfma_f32_16x16x32_bf16(wIhi, bhi, biasL1, 0, 0, 0);
        aH = __builtin_amdgcn_mfma_f32_16x16x32_bf16(wHhi, chi, zero4, 0, 0, 0);
        aI = __builtin_amdgcn_mfma_f32_16x16x32_bf16(wIhi, blo, aI, 0, 0, 0);
        aH = __builtin_amdgcn_mfma_f32_16x16x32_bf16(wHhi, clo, aH, 0, 0, 0);
        aI = __builtin_amdgcn_mfma_f32_16x16x32_bf16(wIlo, bhi, aI, 0, 0, 0);
        aH = __builtin_amdgcn_mfma_f32_16x16x32_bf16(wHlo, chi, aH, 0, 0, 0);
        const f32x4 aL1 = aI + aH;
        const float hv = lstm_nl(aL1, cL1);
        h1f[col][jj] = hv;
        __syncthreads();
    }
#undef PACK_H

    // ---- head: out[b] = fc2( relu( fc1 . h1_T ) ) + fc2_b, by wave 0 ----
    if (wid == 0) {
        float s = 0.0f;
        #pragma unroll
        for (int it = 0; it < 4; ++it) {
            const int r = kq * 4 + it;    // fc1 row in [0,16)
            float acc = fc1_b[r];
            #pragma unroll
            for (int qq = 0; qq < 8; ++qq) {
                const float4 wv = *(const float4*)(fc1_w + r * 32 + qq * 4);
                const float4 hv = *(const float4*)&h1f[col][qq * 4];
                acc += wv.x * hv.x + wv.y * hv.y + wv.z * hv.z + wv.w * hv.w;
            }
            s += fmaxf(acc, 0.0f) * fc2_w[r];
        }
        s += __shfl_xor(s, 16);
        s += __shfl_xor(s, 32);
        if (lane < 16) out[b0 + col] = s + fc2_b[0];
    }
}

extern "C" void kernel_launch(void* const* d_in, const int* in_sizes, int n_in,
                              void* d_out, int out_size, void* d_ws, size_t ws_size,
                              hipStream_t stream) {
    const float* x     = (const float*)d_in[0];
    const float* w_ih0 = (const float*)d_in[1];
    const float* w_hh0 = (const float*)d_in[2];
    const float* b_ih0 = (const float*)d_in[3];
    const float* b_hh0 = (const float*)d_in[4];
    const float* w_ih1 = (const float*)d_in[5];
    const float* w_hh1 = (const float*)d_in[6];
    const float* b_ih1 = (const float*)d_in[7];
    const float* b_hh1 = (const float*)d_in[8];
    const float* fc1_w = (const float*)d_in[9];
    const float* fc1_b = (const float*)d_in[10];
    const float* fc2_w = (const float*)d_in[11];
    const float* fc2_b = (const float*)d_in[12];
    float* out = (float*)d_out;

    dim3 grid(4096 / 16);   // 256 blocks, 1 per CU (batch 4096 / 16 cols)
    dim3 block(512);        // 8 balanced waves -> 2 per SIMD
    hipLaunchKernelGGL(lstm2_mfma, grid, block, 0, stream,
                       x, w_ih0, w_hh0, b_ih0, b_hh0,
                       w_ih1, w_hh1, b_ih1, b_hh1,
                       fc1_w, fc1_b, fc2_w, fc2_b, out);
}